// Round 1
// baseline (2643.229 us; speedup 1.0000x reference)
//
#include <hip/hip_runtime.h>

#define NSEQ 1028
#define TT   256
#define CC   64
#define HH   256
#define FRE  512              // elems per frag-group (64 lanes * 8)
#define KT_REG 3              // k-tiles 0..2 in registers
#define KT_LDS 2              // k-tiles 3..4 in LDS
#define AROW 328              // ushorts per A row (320 + 8 pad)
#define LSTM_LDS (2*16*AROW*2 + KT_LDS*16*4*FRE*2)   // 20992 + 131072 = 152064
#define OUTP_LDS (128*264*2 + 64*264*2)              // 101376

typedef unsigned short u16;
typedef float  f32x4 __attribute__((ext_vector_type(4)));
typedef __bf16 v8bf  __attribute__((ext_vector_type(8)));

__device__ __forceinline__ u16 f2bf(float f){
  unsigned u = __builtin_bit_cast(unsigned, f);
  u += 0x7FFFu + ((u >> 16) & 1u);
  return (u16)(u >> 16);
}
__device__ __forceinline__ float sigm(float x){ return 1.0f/(1.0f+__expf(-x)); }
__device__ __forceinline__ float tanh_f(float x){
  float e = __expf(-2.0f*fabsf(x));
  float r = (1.0f-e)/(1.0f+e);
  return copysignf(r, x);
}

// ---- pack combined W = [W_hh | W_ih] into per-(kt,wave,gate,lane) MFMA frags, bf16
__global__ void k_pack_w(const float* __restrict__ Whh, const float* __restrict__ Wih,
                         u16* __restrict__ wpack){
  int idx = blockIdx.x*256 + threadIdx.x;
  if (idx >= 10*16*4*FRE) return;                 // 327680
  int j    = idx & 7;
  int lane = (idx >> 3) & 63;
  int ct   = (idx >> 9) & 3;
  int w    = (idx >> 11) & 15;
  int kt   = idx >> 15;
  int col  = ct*256 + w*16 + (lane & 15);
  int k    = kt*32 + (lane >> 4)*8 + j;
  float v  = (k < 256) ? Whh[col*256 + k] : Wih[col*64 + (k - 256)];
  wpack[idx] = f2bf(v);
}

__global__ void k_bias(const float* __restrict__ bi, const float* __restrict__ bh,
                       float* __restrict__ bias){
  int i = blockIdx.x*256 + threadIdx.x;
  if (i < 1024) bias[i] = bi[i] + bh[i];
}

__global__ void k_wlin(const float* __restrict__ Wl, u16* __restrict__ wlin){
  int i = blockIdx.x*256 + threadIdx.x;
  if (i >= 64*264) return;
  int col = i / 264, k = i % 264;
  wlin[i] = (k < 256) ? f2bf(Wl[col*256 + k]) : (u16)0;
}

// ---- x(B,C,F,T) -> y(n,t,c) bf16, n = b*257+f
__global__ void k_ytrans(const float* __restrict__ x, u16* __restrict__ ybuf){
  __shared__ u16 tile[64][257];
  int n = blockIdx.x, b = n / 257, f = n % 257, tid = threadIdx.x;
  for (int i = tid; i < 64*256; i += 256){
    int c = i >> 8, t = i & 255;
    tile[c][t] = f2bf(x[((size_t)(b*64 + c)*257 + f)*256 + t]);
  }
  __syncthreads();
  for (int i = tid; i < 256*64; i += 256){
    int t = i >> 6, c = i & 63;
    ybuf[((size_t)n*256 + t)*64 + c] = tile[c][t];
  }
}

// ---- persistent LSTM: 65 blocks x 1024 thr, 16 seqs/block
__global__ __launch_bounds__(1024) void k_lstm(const u16* __restrict__ wpack,
      const float* __restrict__ bias, const u16* __restrict__ ybuf,
      u16* __restrict__ hbuf){
  extern __shared__ char smem[];
  u16* lA = (u16*)smem;                         // [2][16][AROW]
  u16* lW = (u16*)(smem + 2*16*AROW*2);         // kt 3..4 frags
  const int tid = threadIdx.x, lane = tid & 63, w = tid >> 6;
  const int n0 = blockIdx.x * 16;
  const int cr = tid >> 6;                      // coop-copy row role
  const int ccol = tid & 63;
  const int cc4 = (tid & 63) * 4;

  // register-resident W (kt 0..2)
  v8bf wreg[KT_REG][4];
  #pragma unroll
  for (int kt = 0; kt < KT_REG; ++kt)
    #pragma unroll
    for (int ct = 0; ct < 4; ++ct)
      wreg[kt][ct] = *(const v8bf*)(wpack + ((kt*16 + w)*4 + ct)*FRE + lane*8);

  // LDS-resident W (kt 3..4)
  {
    const uint4* src = (const uint4*)(wpack + KT_REG*16*4*FRE);
    uint4* dst = (uint4*)lW;
    for (int i = tid; i < (KT_LDS*16*4*FRE)/8; i += 1024) dst[i] = src[i];
  }
  float biasr[4];
  #pragma unroll
  for (int ct = 0; ct < 4; ++ct) biasr[ct] = bias[ct*256 + w*16 + (lane & 15)];

  { // zero both A buffers
    unsigned* z = (unsigned*)lA;
    for (int i = tid; i < (2*16*AROW)/2; i += 1024) z[i] = 0;
  }
  __syncthreads();
  { // preload y[t=0] into buf0
    u16 v = 0;
    if (n0 + cr < NSEQ) v = ybuf[((size_t)(n0 + cr)*TT + 0)*64 + ccol];
    lA[(0*16 + cr)*AROW + 256 + ccol] = v;
  }
  f32x4 creg = {0.f, 0.f, 0.f, 0.f};
  __syncthreads();

  const int arow_base = (lane & 15) * AROW;
  const int khi = (lane >> 4) * 8;

  for (int t = 0; t < TT; ++t){
    const int cur = t & 1, nxt = cur ^ 1;
    const u16* Acur = lA + cur*16*AROW;
    u16* Anxt = lA + nxt*16*AROW;

    // stream kt5,kt6 issued early (double-buffered global frags)
    v8bf s5[4], s6[4];
    #pragma unroll
    for (int ct = 0; ct < 4; ++ct) s5[ct] = *(const v8bf*)(wpack + ((5*16 + w)*4 + ct)*FRE + lane*8);
    #pragma unroll
    for (int ct = 0; ct < 4; ++ct) s6[ct] = *(const v8bf*)(wpack + ((6*16 + w)*4 + ct)*FRE + lane*8);

    // y prefetch for t+1
    u16 yv = 0;
    if (t + 1 < TT && n0 + cr < NSEQ) yv = ybuf[((size_t)(n0 + cr)*TT + (t + 1))*64 + ccol];

    // copy out h[t-1] (resides in Acur) to global, overlapped with MFMA
    if (t >= 1 && n0 + cr < NSEQ){
      uint2 hv = *(const uint2*)(Acur + cr*AROW + cc4);
      *(uint2*)(hbuf + ((size_t)(n0 + cr)*TT + (t - 1))*HH + cc4) = hv;
    }

    f32x4 acc[4];
    #pragma unroll
    for (int ct = 0; ct < 4; ++ct) acc[ct] = (f32x4){biasr[ct], biasr[ct], biasr[ct], biasr[ct]};

    #pragma unroll
    for (int kt = 0; kt < KT_REG; ++kt){
      v8bf a = *(const v8bf*)(Acur + arow_base + kt*32 + khi);
      #pragma unroll
      for (int ct = 0; ct < 4; ++ct)
        acc[ct] = __builtin_amdgcn_mfma_f32_16x16x32_bf16(a, wreg[kt][ct], acc[ct], 0, 0, 0);
    }
    #pragma unroll
    for (int kt = 3; kt < 5; ++kt){
      v8bf a = *(const v8bf*)(Acur + arow_base + kt*32 + khi);
      #pragma unroll
      for (int ct = 0; ct < 4; ++ct){
        v8bf bfr = *(const v8bf*)(lW + (((kt - 3)*16 + w)*4 + ct)*FRE + lane*8);
        acc[ct] = __builtin_amdgcn_mfma_f32_16x16x32_bf16(a, bfr, acc[ct], 0, 0, 0);
      }
    }
    { // kt5 (s5), refill s5 <- kt7
      v8bf a = *(const v8bf*)(Acur + arow_base + 5*32 + khi);
      #pragma unroll
      for (int ct = 0; ct < 4; ++ct)
        acc[ct] = __builtin_amdgcn_mfma_f32_16x16x32_bf16(a, s5[ct], acc[ct], 0, 0, 0);
      #pragma unroll
      for (int ct = 0; ct < 4; ++ct) s5[ct] = *(const v8bf*)(wpack + ((7*16 + w)*4 + ct)*FRE + lane*8);
    }
    { // kt6 (s6), refill s6 <- kt8
      v8bf a = *(const v8bf*)(Acur + arow_base + 6*32 + khi);
      #pragma unroll
      for (int ct = 0; ct < 4; ++ct)
        acc[ct] = __builtin_amdgcn_mfma_f32_16x16x32_bf16(a, s6[ct], acc[ct], 0, 0, 0);
      #pragma unroll
      for (int ct = 0; ct < 4; ++ct) s6[ct] = *(const v8bf*)(wpack + ((8*16 + w)*4 + ct)*FRE + lane*8);
    }
    { // kt7 (s5), refill s5 <- kt9
      v8bf a = *(const v8bf*)(Acur + arow_base + 7*32 + khi);
      #pragma unroll
      for (int ct = 0; ct < 4; ++ct)
        acc[ct] = __builtin_amdgcn_mfma_f32_16x16x32_bf16(a, s5[ct], acc[ct], 0, 0, 0);
      #pragma unroll
      for (int ct = 0; ct < 4; ++ct) s5[ct] = *(const v8bf*)(wpack + ((9*16 + w)*4 + ct)*FRE + lane*8);
    }
    { // kt8 (s6)
      v8bf a = *(const v8bf*)(Acur + arow_base + 8*32 + khi);
      #pragma unroll
      for (int ct = 0; ct < 4; ++ct)
        acc[ct] = __builtin_amdgcn_mfma_f32_16x16x32_bf16(a, s6[ct], acc[ct], 0, 0, 0);
    }
    { // kt9 (s5)
      v8bf a = *(const v8bf*)(Acur + arow_base + 9*32 + khi);
      #pragma unroll
      for (int ct = 0; ct < 4; ++ct)
        acc[ct] = __builtin_amdgcn_mfma_f32_16x16x32_bf16(a, s5[ct], acc[ct], 0, 0, 0);
    }

    // elementwise LSTM cell; lane owns unit u = w*16+(lane&15), seqs 4*(lane>>4)+j
    #pragma unroll
    for (int j = 0; j < 4; ++j){
      float xi = acc[0][j], xf = acc[1][j], xg = acc[2][j], xo = acc[3][j];
      float cv = sigm(xf)*creg[j] + sigm(xi)*tanh_f(xg);
      float hv = sigm(xo)*tanh_f(cv);
      creg[j] = cv;
      Anxt[(4*(lane >> 4) + j)*AROW + (w*16 + (lane & 15))] = f2bf(hv);
    }
    // stage y[t+1]
    Anxt[cr*AROW + 256 + ccol] = yv;
    __syncthreads();
  }
  // final h[255] sits in lA buf0
  if (n0 + cr < NSEQ){
    uint2 hv = *(const uint2*)(lA + cr*AROW + cc4);
    *(uint2*)(hbuf + ((size_t)(n0 + cr)*TT + 255)*HH + cc4) = hv;
  }
}

// ---- out = h @ W_lin^T + b_lin, written as (B,OUT,F,T)
__global__ __launch_bounds__(256) void k_outproj(const u16* __restrict__ hbuf,
      const u16* __restrict__ wlin, const float* __restrict__ blin,
      float* __restrict__ out){
  extern __shared__ char smem[];
  u16* sA = (u16*)smem;                 // [128][264] rows = t
  u16* sB = (u16*)(smem + 128*264*2);   // [64][264]  rows = o
  const int n = blockIdx.x, th = blockIdx.y, t0 = th*128;
  const int b = n / 257, f = n % 257;
  const int tid = threadIdx.x, lane = tid & 63, wv = tid >> 6;

  for (int i = tid; i < 128*32; i += 256){      // 16B chunks
    int r = i >> 5, part = i & 31;
    *(uint4*)(sA + r*264 + part*8) =
        *(const uint4*)(hbuf + ((size_t)n*TT + t0 + r)*HH + part*8);
  }
  for (int i = tid; i < (64*264)/2; i += 256)
    ((unsigned*)sB)[i] = ((const unsigned*)wlin)[i];
  __syncthreads();

  f32x4 acc[2][4];
  #pragma unroll
  for (int m = 0; m < 2; ++m)
    #pragma unroll
    for (int nt = 0; nt < 4; ++nt){
      float bv = blin[nt*16 + (lane & 15)];
      acc[m][nt] = (f32x4){bv, bv, bv, bv};
    }
  const int khi = (lane >> 4) * 8;
  #pragma unroll
  for (int kt = 0; kt < 8; ++kt){
    v8bf av[2];
    #pragma unroll
    for (int m = 0; m < 2; ++m){
      int mt = wv*2 + m;
      av[m] = *(const v8bf*)(sA + (mt*16 + (lane & 15))*264 + kt*32 + khi);
    }
    #pragma unroll
    for (int nt = 0; nt < 4; ++nt){
      v8bf bv = *(const v8bf*)(sB + (nt*16 + (lane & 15))*264 + kt*32 + khi);
      #pragma unroll
      for (int m = 0; m < 2; ++m)
        acc[m][nt] = __builtin_amdgcn_mfma_f32_16x16x32_bf16(av[m], bv, acc[m][nt], 0, 0, 0);
    }
  }
  #pragma unroll
  for (int m = 0; m < 2; ++m){
    int mt = wv*2 + m;
    #pragma unroll
    for (int nt = 0; nt < 4; ++nt){
      int o = nt*16 + (lane & 15);
      int tb = t0 + mt*16 + 4*(lane >> 4);
      *(f32x4*)(out + (((size_t)b*64 + o)*257 + f)*TT + tb) = acc[m][nt];
    }
  }
}

extern "C" void kernel_launch(void* const* d_in, const int* in_sizes, int n_in,
                              void* d_out, int out_size, void* d_ws, size_t ws_size,
                              hipStream_t stream) {
  const float* x   = (const float*)d_in[0];
  const float* Wih = (const float*)d_in[1];
  const float* Whh = (const float*)d_in[2];
  const float* bih = (const float*)d_in[3];
  const float* bhh = (const float*)d_in[4];
  const float* Wl  = (const float*)d_in[5];
  const float* bl  = (const float*)d_in[6];
  float* out = (float*)d_out;

  char* p = (char*)d_ws;
  u16*   wpack = (u16*)p;   p += 655360;                 // 10*16*4*512*2
  float* bias  = (float*)p; p += 4096;
  u16*   wlin  = (u16*)p;   p += 33792;                  // 64*264*2
  u16*   ybuf  = (u16*)p;   p += (size_t)NSEQ*TT*CC*2;   // 33.7 MB
  u16*   hbuf  = (u16*)p;                                // 134.7 MB

  hipFuncSetAttribute((const void*)k_lstm,    hipFuncAttributeMaxDynamicSharedMemorySize, LSTM_LDS);
  hipFuncSetAttribute((const void*)k_outproj, hipFuncAttributeMaxDynamicSharedMemorySize, OUTP_LDS);

  k_pack_w <<<1280, 256, 0, stream>>>(Whh, Wih, wpack);
  k_bias   <<<4,    256, 0, stream>>>(bih, bhh, bias);
  k_wlin   <<<66,   256, 0, stream>>>(Wl, wlin);
  k_ytrans <<<1028, 256, 0, stream>>>(x, ybuf);
  k_lstm   <<<65, 1024, LSTM_LDS, stream>>>(wpack, bias, ybuf, hbuf);
  k_outproj<<<dim3(1028, 2), 256, OUTP_LDS, stream>>>(hbuf, wlin, bl, out);
}